// Round 1
// baseline (711.669 us; speedup 1.0000x reference)
//
#include <hip/hip_runtime.h>
#include <cstdint>
#include <cstddef>

typedef unsigned short u16;
typedef __attribute__((ext_vector_type(8))) __bf16 bf16x8;
typedef __attribute__((ext_vector_type(4))) float f32x4;

#define DD 1024            // D
#define MM 16384           // B*T rows
#define NCH 64             // scan chunks
#define CLEN 64            // chunk length (NCH*CLEN = T = 4096)

__device__ __forceinline__ u16 f2b(float f) {
    uint32_t u = __float_as_uint(f);
    u += 0x7fffu + ((u >> 16) & 1u);       // round-to-nearest-even
    return (u16)(u >> 16);
}
__device__ __forceinline__ float b2f(u16 v) {
    return __uint_as_float(((uint32_t)v) << 16);
}
__device__ __forceinline__ float sigmoid_f(float v) { return 1.f / (1.f + __expf(-v)); }
__device__ __forceinline__ float gelu_f(float v) {
    return 0.5f * v * (1.f + erff(v * 0.70710678118654752f));
}

__device__ __forceinline__ void glds16(const u16* g, u16* l) {
    __builtin_amdgcn_global_load_lds(
        (const __attribute__((address_space(1))) void*)g,
        (__attribute__((address_space(3))) void*)l, 16, 0, 0);
}

// ---------------------------------------------------------------------------
// NT GEMM: out[m,n] = sum_k A[m,k]*W[n,k] + bias[n], A/W bf16 row-major,
// M=16384, N=K=1024. 128x128 tile, BK=32, 256 threads (4 waves, 2x2 of 64x64).
// MODE: 0 plain->bf16, 1 sigmoid->bf16, 2 (+bias+auxf)->f32,
//       3 gelu(sigmoid)->bf16, 4 auxb*(v)->bf16, 5 (+bias+auxf)->f32 (final)
// ---------------------------------------------------------------------------
template <int MODE>
__global__ __launch_bounds__(256, 2)
void gemm_bt(const u16* __restrict__ A, const u16* __restrict__ Bw,
             const float* __restrict__ bias,
             const float* __restrict__ auxf, const u16* __restrict__ auxb,
             u16* __restrict__ outb, float* __restrict__ outf)
{
    const int K = DD, N = DD;
    __shared__ __align__(16) u16 As[128 * 32];
    __shared__ __align__(16) u16 Bs[128 * 32];

    const int tid = threadIdx.x;
    const int m0 = blockIdx.y * 128, n0 = blockIdx.x * 128;
    const int wave = tid >> 6, lane = tid & 63;
    const int wm = (wave >> 1) * 64, wn = (wave & 1) * 64;
    const int lr = lane & 15, lq = lane >> 4;

    // staging: flat index f in [0,512), 16B each; row=f>>2, col8=(f&3)*8
    const u16* Ag = A + (size_t)(m0 + (tid >> 2)) * K + (tid & 3) * 8;
    const u16* Bg = Bw + (size_t)(n0 + (tid >> 2)) * K + (tid & 3) * 8;
    u16* la0 = &As[tid * 8];
    u16* la1 = &As[(tid + 256) * 8];
    u16* lb0 = &Bs[tid * 8];
    u16* lb1 = &Bs[(tid + 256) * 8];

    f32x4 acc[4][4] = {};

    for (int k0 = 0; k0 < K; k0 += 32) {
        glds16(Ag + k0, la0);
        glds16(Ag + (size_t)64 * K + k0, la1);
        glds16(Bg + k0, lb0);
        glds16(Bg + (size_t)64 * K + k0, lb1);
        __syncthreads();   // drains vmcnt before barrier

        bf16x8 av[4], bv[4];
#pragma unroll
        for (int i = 0; i < 4; i++)
            av[i] = *(const bf16x8*)&As[(wm + i * 16 + lr) * 32 + lq * 8];
#pragma unroll
        for (int j = 0; j < 4; j++)
            bv[j] = *(const bf16x8*)&Bs[(wn + j * 16 + lr) * 32 + lq * 8];
#pragma unroll
        for (int i = 0; i < 4; i++)
#pragma unroll
            for (int j = 0; j < 4; j++)
                acc[i][j] = __builtin_amdgcn_mfma_f32_16x16x32_bf16(
                    av[i], bv[j], acc[i][j], 0, 0, 0);
        __syncthreads();
    }

    // epilogue: C/D layout col=lane&15, row=(lane>>4)*4+reg
#pragma unroll
    for (int i = 0; i < 4; i++) {
        const int mrow = m0 + wm + i * 16 + lq * 4;
#pragma unroll
        for (int j = 0; j < 4; j++) {
            const int ncol = n0 + wn + j * 16 + lr;
            const float bz = bias[ncol];
#pragma unroll
            for (int p = 0; p < 4; p++) {
                const size_t idx = (size_t)(mrow + p) * N + ncol;
                float v = acc[i][j][p] + bz;
                if constexpr (MODE == 0) {
                    outb[idx] = f2b(v);
                } else if constexpr (MODE == 1) {
                    outb[idx] = f2b(sigmoid_f(v));
                } else if constexpr (MODE == 2) {
                    outf[idx] = v + auxf[idx];
                } else if constexpr (MODE == 3) {
                    outb[idx] = f2b(gelu_f(sigmoid_f(v)));
                } else if constexpr (MODE == 4) {
                    outb[idx] = f2b(b2f(auxb[idx]) * v);
                } else {
                    outf[idx] = v + auxf[idx];
                }
            }
        }
    }
}

// ---------------------------------------------------------------------------
// RMSNorm: one block per row; out bf16 = x/max(||x||,1e-12)*sqrt(D)*g
// ---------------------------------------------------------------------------
__global__ __launch_bounds__(256)
void rmsnorm_k(const float* __restrict__ x, const float* __restrict__ g,
               u16* __restrict__ out)
{
    const int row = blockIdx.x;
    const int t = threadIdx.x;
    const float4 v = ((const float4*)(x + (size_t)row * DD))[t];
    float ss = v.x * v.x + v.y * v.y + v.z * v.z + v.w * v.w;
#pragma unroll
    for (int o = 32; o > 0; o >>= 1) ss += __shfl_down(ss, o, 64);
    __shared__ float wsum[4];
    if ((t & 63) == 0) wsum[t >> 6] = ss;
    __syncthreads();
    const float tot = wsum[0] + wsum[1] + wsum[2] + wsum[3];
    const float sc = 32.0f * rsqrtf(fmaxf(tot, 1e-24f));
    const float4 gv = ((const float4*)g)[t];
    ushort4 o4;
    o4.x = f2b(v.x * sc * gv.x);
    o4.y = f2b(v.y * sc * gv.y);
    o4.z = f2b(v.z * sc * gv.z);
    o4.w = f2b(v.w * sc * gv.w);
    ((ushort4*)(out + (size_t)row * DD))[t] = o4;
}

// ---------------------------------------------------------------------------
// fp32 -> bf16 weight conversion (1M elements per launch)
// ---------------------------------------------------------------------------
__global__ __launch_bounds__(256)
void conv_w(const float* __restrict__ in, u16* __restrict__ out)
{
    const int i = (blockIdx.x * 256 + threadIdx.x) * 4;
    const float4 v = *(const float4*)(in + i);
    ushort4 o;
    o.x = f2b(v.x); o.y = f2b(v.y); o.z = f2b(v.z); o.w = f2b(v.w);
    *(ushort4*)(out + i) = o;
}

// ---------------------------------------------------------------------------
// RG-LRU chunked scan. h[t] = a[t]*h[t-1] + g[t]
// a = exp(log_a * rt / 8), log_a = -softplus(-Lam[d])
// g = sqrt(1-a^2) * it * x_rg
// Pass 1: per (b,chunk,d): local product P and local scan last value Hl
// Pass 2: per (b,d): carry-in per chunk
// Pass 3: re-scan with carry, emit yin = gelu(lin)*h (bf16)
// ---------------------------------------------------------------------------
__global__ __launch_bounds__(256)
void scan_chunks(const u16* __restrict__ rt, const u16* __restrict__ it,
                 const u16* __restrict__ rg, const float* __restrict__ Lam,
                 float* __restrict__ P, float* __restrict__ Hl)
{
    const int d = blockIdx.x * 256 + threadIdx.x;
    const int c = blockIdx.y, b = blockIdx.z;
    const float k = -log1pf(__expf(-Lam[d])) * 0.125f;
    const size_t base = (((size_t)b * 4096) + (size_t)c * CLEN) * DD + d;
    float p = 1.f, h = 0.f;
#pragma unroll 4
    for (int t = 0; t < CLEN; t++) {
        const size_t ix = base + (size_t)t * DD;
        const float r = b2f(rt[ix]);
        const float i = b2f(it[ix]);
        const float xv = b2f(rg[ix]);
        const float a = __expf(k * r);
        const float g = sqrtf(fmaxf(1.f - a * a, 0.f)) * (i * xv);
        p *= a;
        h = fmaf(a, h, g);
    }
    const int o = (b * NCH + c) * DD + d;
    P[o] = p;
    Hl[o] = h;
}

__global__ __launch_bounds__(256)
void scan_carry(const float* __restrict__ P, const float* __restrict__ Hl,
                float* __restrict__ Cin)
{
    const int idx = blockIdx.x * 256 + threadIdx.x;  // B*D = 4096
    const int b = idx >> 10, d = idx & 1023;
    float h = 0.f;
    for (int c = 0; c < NCH; c++) {
        const int o = (b * NCH + c) * DD + d;
        Cin[o] = h;
        h = fmaf(P[o], h, Hl[o]);
    }
}

__global__ __launch_bounds__(256)
void scan_apply(const u16* __restrict__ rt, const u16* __restrict__ it,
                const u16* __restrict__ rg, const u16* __restrict__ lin,
                const float* __restrict__ Lam, const float* __restrict__ Cin,
                u16* __restrict__ yin)
{
    const int d = blockIdx.x * 256 + threadIdx.x;
    const int c = blockIdx.y, b = blockIdx.z;
    const float k = -log1pf(__expf(-Lam[d])) * 0.125f;
    const size_t base = (((size_t)b * 4096) + (size_t)c * CLEN) * DD + d;
    float h = Cin[(b * NCH + c) * DD + d];
#pragma unroll 4
    for (int t = 0; t < CLEN; t++) {
        const size_t ix = base + (size_t)t * DD;
        const float r = b2f(rt[ix]);
        const float i = b2f(it[ix]);
        const float xv = b2f(rg[ix]);
        const float a = __expf(k * r);
        const float g = sqrtf(fmaxf(1.f - a * a, 0.f)) * (i * xv);
        h = fmaf(a, h, g);
        const float l = b2f(lin[ix]);
        yin[ix] = f2b(gelu_f(l) * h);
    }
}

// ---------------------------------------------------------------------------
extern "C" void kernel_launch(void* const* d_in, const int* in_sizes, int n_in,
                              void* d_out, int out_size, void* d_ws, size_t ws_size,
                              hipStream_t stream)
{
    const float* x      = (const float*)d_in[0];
    const float* g1     = (const float*)d_in[1];
    const float* g2     = (const float*)d_in[2];
    const float* W_lin  = (const float*)d_in[3];
    const float* b_lin  = (const float*)d_in[4];
    const float* W_conv = (const float*)d_in[5];
    const float* b_conv = (const float*)d_in[6];
    const float* W_lin2 = (const float*)d_in[7];
    const float* b_lin2 = (const float*)d_in[8];
    const float* Wa     = (const float*)d_in[9];
    const float* ba     = (const float*)d_in[10];
    const float* Wx     = (const float*)d_in[11];
    const float* bx     = (const float*)d_in[12];
    const float* Lam    = (const float*)d_in[13];
    const float* W1     = (const float*)d_in[14];
    const float* b1     = (const float*)d_in[15];
    const float* W2     = (const float*)d_in[16];
    const float* b2     = (const float*)d_in[17];
    const float* W3     = (const float*)d_in[18];
    const float* b3     = (const float*)d_in[19];
    float* out = (float*)d_out;

    char* p = (char*)d_ws;
    auto alloc = [&](size_t bytes) -> char* {
        char* q = p;
        p += (bytes + 255) & ~(size_t)255;
        return q;
    };
    const size_t MD = (size_t)MM * DD;
    u16* wbf[8];
    for (int i = 0; i < 8; i++) wbf[i] = (u16*)alloc((size_t)DD * DD * 2);
    u16* t0 = (u16*)alloc(MD * 2);
    u16* t1 = (u16*)alloc(MD * 2);
    u16* t2 = (u16*)alloc(MD * 2);
    u16* t3 = (u16*)alloc(MD * 2);
    u16* t4 = (u16*)alloc(MD * 2);
    float* res2 = (float*)alloc(MD * 4);
    float* P   = (float*)alloc((size_t)4 * NCH * DD * 4);
    float* Hl  = (float*)alloc((size_t)4 * NCH * DD * 4);
    float* Cin = (float*)alloc((size_t)4 * NCH * DD * 4);

    // weights -> bf16
    const float* wsrc[8] = {W_lin, W_conv, Wa, Wx, W_lin2, W1, W2, W3};
    for (int i = 0; i < 8; i++)
        conv_w<<<(DD * DD) / 1024, 256, 0, stream>>>(wsrc[i], wbf[i]);

    const dim3 gg(DD / 128, MM / 128);
    const dim3 sg(DD / 256, NCH, 4);

    // xn = rmsnorm(x)*g1
    rmsnorm_k<<<MM, 256, 0, stream>>>(x, g1, t0);
    // lin = xn@W_lin.T + b_lin
    gemm_bt<0><<<gg, 256, 0, stream>>>(t0, wbf[0], b_lin, nullptr, nullptr, t1, nullptr);
    // rg = lin@W_conv.T + b_conv
    gemm_bt<0><<<gg, 256, 0, stream>>>(t1, wbf[1], b_conv, nullptr, nullptr, t2, nullptr);
    // rt = sigmoid(rg@Wa.T + ba)
    gemm_bt<1><<<gg, 256, 0, stream>>>(t2, wbf[2], ba, nullptr, nullptr, t0, nullptr);
    // it = sigmoid(rg@Wx.T + bx)
    gemm_bt<1><<<gg, 256, 0, stream>>>(t2, wbf[3], bx, nullptr, nullptr, t3, nullptr);
    // RG-LRU scan + yin = gelu(lin)*h
    scan_chunks<<<sg, 256, 0, stream>>>(t0, t3, t2, Lam, P, Hl);
    scan_carry<<<4096 / 256, 256, 0, stream>>>(P, Hl, Cin);
    scan_apply<<<sg, 256, 0, stream>>>(t0, t3, t2, t1, Lam, Cin, t4);
    // res2 = yin@W_lin2.T + b_lin2 + x
    gemm_bt<2><<<gg, 256, 0, stream>>>(t4, wbf[4], b_lin2, x, nullptr, nullptr, res2);
    // xm = rmsnorm(res2)*g2
    rmsnorm_k<<<MM, 256, 0, stream>>>(res2, g2, t0);
    // gate = gelu(sigmoid(xm@W1.T + b1))
    gemm_bt<3><<<gg, 256, 0, stream>>>(t0, wbf[5], b1, nullptr, nullptr, t1, nullptr);
    // combined = gate * (xm@W2.T + b2)
    gemm_bt<4><<<gg, 256, 0, stream>>>(t0, wbf[6], b2, nullptr, t1, t2, nullptr);
    // y = combined@W3.T + b3 + res2
    gemm_bt<5><<<gg, 256, 0, stream>>>(t2, wbf[7], b3, res2, nullptr, nullptr, out);
}

// Round 2
// 654.631 us; speedup vs baseline: 1.0871x; 1.0871x over previous
//
#include <hip/hip_runtime.h>
#include <cstdint>
#include <cstddef>

typedef unsigned short u16;
typedef __attribute__((ext_vector_type(8))) __bf16 bf16x8;
typedef __attribute__((ext_vector_type(4))) float f32x4;

#define DD 1024            // D
#define MM 16384           // B*T rows
#define NCH 64             // scan chunks
#define CLEN 64            // chunk length (NCH*CLEN = T = 4096)
#define EPAD 136           // epilogue LDS row stride in u16 (16B-aligned, bank-spread)

__device__ __forceinline__ u16 f2b(float f) {
    uint32_t u = __float_as_uint(f);
    u += 0x7fffu + ((u >> 16) & 1u);       // round-to-nearest-even
    return (u16)(u >> 16);
}
__device__ __forceinline__ float b2f(u16 v) {
    return __uint_as_float(((uint32_t)v) << 16);
}
__device__ __forceinline__ float sigmoid_f(float v) { return 1.f / (1.f + __expf(-v)); }
__device__ __forceinline__ float gelu_f(float v) {
    return 0.5f * v * (1.f + erff(v * 0.70710678118654752f));
}

__device__ __forceinline__ void glds16(const u16* g, u16* l) {
    __builtin_amdgcn_global_load_lds(
        (const __attribute__((address_space(1))) void*)g,
        (__attribute__((address_space(3))) void*)l, 16, 0, 0);
}

// Block swizzle: groups of 64 blocks = 8 m-tiles x 8 n-tiles. With round-robin
// l%8 -> XCD, each XCD's local sequence covers one m-tile across all 8 n-tiles
// (A-tile stays in that XCD's L2; W working set ~2MB also L2-resident).
__device__ __forceinline__ void swiz(int l, int& mt, int& nt) {
    const int g = l >> 6, r = l & 63;
    mt = g * 8 + (r & 7);
    nt = r >> 3;
}

// ---------------------------------------------------------------------------
// NT GEMM: out[m,n] = sum_k A[m,k]*W[n,k] + bias[n]. M=16384, N=K=1024.
// 128x128 tile, BK=32, 256 threads (4 waves, 2x2 of 64x64).
// LDS layout XOR-swizzled: (row, kb) stored at slot row*4 + (kb ^ ((row>>1)&3))
// so each quarter-wave ds_read_b128 spreads across all 32 banks.
// MODE 0: bf16 out via LDS-staged coalesced write
// MODE 2: f32 out = v + bias + auxf[idx]
// ---------------------------------------------------------------------------
template <int MODE>
__global__ __launch_bounds__(256, 2)
void gemm_bt(const u16* __restrict__ A, const u16* __restrict__ Bw,
             const float* __restrict__ bias, const float* __restrict__ auxf,
             u16* __restrict__ outb, float* __restrict__ outf)
{
    const int K = DD, N = DD;
    __shared__ __align__(16) u16 smem[8704];   // As[0:4096), Bs[4096:8192); epi 64*136
    u16* As = smem;
    u16* Bs = smem + 4096;

    int mt, nt; swiz(blockIdx.x, mt, nt);
    const int m0 = mt * 128, n0 = nt * 128;
    const int tid = threadIdx.x;
    const int wave = tid >> 6, lane = tid & 63;
    const int wm = (wave >> 1) * 64, wn = (wave & 1) * 64;
    const int lr = lane & 15, lq = lane >> 4;

    // staging: thread stages LDS slot (trow, tcol); global kb = tcol ^ ((trow>>1)&3)
    const int trow = tid >> 2, tcol = tid & 3;
    const int kswz = (tcol ^ ((trow >> 1) & 3)) * 8;
    const u16* Ag = A + (size_t)(m0 + trow) * K + kswz;
    const u16* Bg = Bw + (size_t)(n0 + trow) * K + kswz;
    u16* la0 = &As[tid * 8];
    u16* la1 = &As[tid * 8 + 2048];
    u16* lb0 = &Bs[tid * 8];
    u16* lb1 = &Bs[tid * 8 + 2048];

    f32x4 acc[4][4] = {};

    for (int k0 = 0; k0 < K; k0 += 32) {
        glds16(Ag + k0, la0);
        glds16(Ag + (size_t)64 * K + k0, la1);
        glds16(Bg + k0, lb0);
        glds16(Bg + (size_t)64 * K + k0, lb1);
        __syncthreads();

        bf16x8 av[4], bv[4];
        const int cs = (lq ^ ((lr >> 1) & 3)) * 8;
#pragma unroll
        for (int i = 0; i < 4; i++)
            av[i] = *(const bf16x8*)&As[(wm + i * 16 + lr) * 32 + cs];
#pragma unroll
        for (int j = 0; j < 4; j++)
            bv[j] = *(const bf16x8*)&Bs[(wn + j * 16 + lr) * 32 + cs];
#pragma unroll
        for (int i = 0; i < 4; i++)
#pragma unroll
            for (int j = 0; j < 4; j++)
                acc[i][j] = __builtin_amdgcn_mfma_f32_16x16x32_bf16(
                    av[i], bv[j], acc[i][j], 0, 0, 0);
        __syncthreads();
    }

    // epilogue: C/D layout col=lane&15, row=(lane>>4)*4+reg
    if constexpr (MODE == 0) {
        for (int half = 0; half < 2; half++) {
            __syncthreads();
            if (wm == half * 64) {
#pragma unroll
                for (int i = 0; i < 4; i++)
#pragma unroll
                    for (int j = 0; j < 4; j++) {
                        const int col = wn + j * 16 + lr;
                        const float bz = bias[n0 + col];
#pragma unroll
                        for (int p = 0; p < 4; p++)
                            smem[(i * 16 + lq * 4 + p) * EPAD + col] =
                                f2b(acc[i][j][p] + bz);
                    }
            }
            __syncthreads();
#pragma unroll
            for (int t = 0; t < 4; t++) {
                const int f = t * 256 + tid;
                const int row = f >> 4, c8 = (f & 15) * 8;
                *(uint4*)&outb[(size_t)(m0 + half * 64 + row) * N + n0 + c8] =
                    *(const uint4*)&smem[row * EPAD + c8];
            }
        }
    } else {
#pragma unroll
        for (int i = 0; i < 4; i++) {
            const int mrow = m0 + wm + i * 16 + lq * 4;
#pragma unroll
            for (int j = 0; j < 4; j++) {
                const int ncol = n0 + wn + j * 16 + lr;
                const float bz = bias[ncol];
#pragma unroll
                for (int p = 0; p < 4; p++) {
                    const size_t idx = (size_t)(mrow + p) * N + ncol;
                    outf[idx] = acc[i][j][p] + bz + auxf[idx];
                }
            }
        }
    }
}

// ---------------------------------------------------------------------------
// Dual GEMM: same A, two weight matrices, fused epilogue.
// DMODE 0: out1 = sigmoid(A@B1^T+b1), out2 = sigmoid(A@B2^T+b2)  (rt, it)
// DMODE 1: out1 = gelu(sigmoid(A@B1^T+b1)) * (A@B2^T+b2)         (combined)
// ---------------------------------------------------------------------------
template <int DMODE>
__global__ __launch_bounds__(256, 2)
void gemm_dual(const u16* __restrict__ A, const u16* __restrict__ B1,
               const u16* __restrict__ B2,
               const float* __restrict__ bias1, const float* __restrict__ bias2,
               u16* __restrict__ out1, u16* __restrict__ out2)
{
    const int K = DD, N = DD;
    __shared__ __align__(16) u16 smem[12288];  // As, Bs1, Bs2 (4096 each); epi 8704
    u16* As = smem;
    u16* Bs1 = smem + 4096;
    u16* Bs2 = smem + 8192;

    int mt, nt; swiz(blockIdx.x, mt, nt);
    const int m0 = mt * 128, n0 = nt * 128;
    const int tid = threadIdx.x;
    const int wave = tid >> 6, lane = tid & 63;
    const int wm = (wave >> 1) * 64, wn = (wave & 1) * 64;
    const int lr = lane & 15, lq = lane >> 4;

    const int trow = tid >> 2, tcol = tid & 3;
    const int kswz = (tcol ^ ((trow >> 1) & 3)) * 8;
    const u16* Ag  = A  + (size_t)(m0 + trow) * K + kswz;
    const u16* B1g = B1 + (size_t)(n0 + trow) * K + kswz;
    const u16* B2g = B2 + (size_t)(n0 + trow) * K + kswz;
    u16* la0 = &As[tid * 8];
    u16* la1 = &As[tid * 8 + 2048];
    u16* lb10 = &Bs1[tid * 8];
    u16* lb11 = &Bs1[tid * 8 + 2048];
    u16* lb20 = &Bs2[tid * 8];
    u16* lb21 = &Bs2[tid * 8 + 2048];

    f32x4 acc1[4][4] = {}, acc2[4][4] = {};

    for (int k0 = 0; k0 < K; k0 += 32) {
        glds16(Ag + k0, la0);
        glds16(Ag + (size_t)64 * K + k0, la1);
        glds16(B1g + k0, lb10);
        glds16(B1g + (size_t)64 * K + k0, lb11);
        glds16(B2g + k0, lb20);
        glds16(B2g + (size_t)64 * K + k0, lb21);
        __syncthreads();

        bf16x8 av[4], bv1[4], bv2[4];
        const int cs = (lq ^ ((lr >> 1) & 3)) * 8;
#pragma unroll
        for (int i = 0; i < 4; i++)
            av[i] = *(const bf16x8*)&As[(wm + i * 16 + lr) * 32 + cs];
#pragma unroll
        for (int j = 0; j < 4; j++) {
            bv1[j] = *(const bf16x8*)&Bs1[(wn + j * 16 + lr) * 32 + cs];
            bv2[j] = *(const bf16x8*)&Bs2[(wn + j * 16 + lr) * 32 + cs];
        }
#pragma unroll
        for (int i = 0; i < 4; i++)
#pragma unroll
            for (int j = 0; j < 4; j++) {
                acc1[i][j] = __builtin_amdgcn_mfma_f32_16x16x32_bf16(
                    av[i], bv1[j], acc1[i][j], 0, 0, 0);
                acc2[i][j] = __builtin_amdgcn_mfma_f32_16x16x32_bf16(
                    av[i], bv2[j], acc2[i][j], 0, 0, 0);
            }
        __syncthreads();
    }

    if constexpr (DMODE == 0) {
#pragma unroll
        for (int o = 0; o < 2; o++) {
            const float* bz = o ? bias2 : bias1;
            u16* op = o ? out2 : out1;
            for (int half = 0; half < 2; half++) {
                __syncthreads();
                if (wm == half * 64) {
#pragma unroll
                    for (int i = 0; i < 4; i++)
#pragma unroll
                        for (int j = 0; j < 4; j++) {
                            const int col = wn + j * 16 + lr;
                            const float bb = bz[n0 + col];
#pragma unroll
                            for (int p = 0; p < 4; p++) {
                                const float v = (o ? acc2[i][j][p] : acc1[i][j][p]) + bb;
                                smem[(i * 16 + lq * 4 + p) * EPAD + col] = f2b(sigmoid_f(v));
                            }
                        }
                }
                __syncthreads();
#pragma unroll
                for (int t = 0; t < 4; t++) {
                    const int f = t * 256 + tid;
                    const int row = f >> 4, c8 = (f & 15) * 8;
                    *(uint4*)&op[(size_t)(m0 + half * 64 + row) * N + n0 + c8] =
                        *(const uint4*)&smem[row * EPAD + c8];
                }
            }
        }
    } else {
        for (int half = 0; half < 2; half++) {
            __syncthreads();
            if (wm == half * 64) {
#pragma unroll
                for (int i = 0; i < 4; i++)
#pragma unroll
                    for (int j = 0; j < 4; j++) {
                        const int col = wn + j * 16 + lr;
                        const float bb1 = bias1[n0 + col];
                        const float bb2 = bias2[n0 + col];
#pragma unroll
                        for (int p = 0; p < 4; p++) {
                            const float g = gelu_f(sigmoid_f(acc1[i][j][p] + bb1));
                            smem[(i * 16 + lq * 4 + p) * EPAD + col] =
                                f2b(g * (acc2[i][j][p] + bb2));
                        }
                    }
            }
            __syncthreads();
#pragma unroll
            for (int t = 0; t < 4; t++) {
                const int f = t * 256 + tid;
                const int row = f >> 4, c8 = (f & 15) * 8;
                *(uint4*)&out1[(size_t)(m0 + half * 64 + row) * N + n0 + c8] =
                    *(const uint4*)&smem[row * EPAD + c8];
            }
        }
    }
}

// ---------------------------------------------------------------------------
// RMSNorm: one block per row; out bf16 = x/max(||x||,1e-12)*sqrt(D)*g
// ---------------------------------------------------------------------------
__global__ __launch_bounds__(256)
void rmsnorm_k(const float* __restrict__ x, const float* __restrict__ g,
               u16* __restrict__ out)
{
    const int row = blockIdx.x;
    const int t = threadIdx.x;
    const float4 v = ((const float4*)(x + (size_t)row * DD))[t];
    float ss = v.x * v.x + v.y * v.y + v.z * v.z + v.w * v.w;
#pragma unroll
    for (int o = 32; o > 0; o >>= 1) ss += __shfl_down(ss, o, 64);
    __shared__ float wsum[4];
    if ((t & 63) == 0) wsum[t >> 6] = ss;
    __syncthreads();
    const float tot = wsum[0] + wsum[1] + wsum[2] + wsum[3];
    const float sc = 32.0f * rsqrtf(fmaxf(tot, 1e-24f));
    const float4 gv = ((const float4*)g)[t];
    ushort4 o4;
    o4.x = f2b(v.x * sc * gv.x);
    o4.y = f2b(v.y * sc * gv.y);
    o4.z = f2b(v.z * sc * gv.z);
    o4.w = f2b(v.w * sc * gv.w);
    ((ushort4*)(out + (size_t)row * DD))[t] = o4;
}

// ---------------------------------------------------------------------------
// fp32 -> bf16 conversion of all 8 weight matrices in one launch
// ---------------------------------------------------------------------------
struct W8 { const float* s[8]; };
__global__ __launch_bounds__(256)
void conv_w8(W8 w, u16* __restrict__ out)
{
    const float* in = w.s[blockIdx.y];
    u16* o = out + (size_t)blockIdx.y * DD * DD;
    const int i = (blockIdx.x * 256 + threadIdx.x) * 4;
    const float4 v = *(const float4*)(in + i);
    ushort4 r;
    r.x = f2b(v.x); r.y = f2b(v.y); r.z = f2b(v.z); r.w = f2b(v.w);
    *(ushort4*)(o + i) = r;
}

// ---------------------------------------------------------------------------
// RG-LRU chunked scan. h[t] = a[t]*h[t-1] + g[t]
// a = exp(log_a * rt / 8), log_a = -softplus(-Lam[d])
// g = sqrt(1-a^2) * it * x_rg
// ---------------------------------------------------------------------------
__global__ __launch_bounds__(256)
void scan_chunks(const u16* __restrict__ rt, const u16* __restrict__ it,
                 const u16* __restrict__ rg, const float* __restrict__ Lam,
                 float* __restrict__ P, float* __restrict__ Hl)
{
    const int d = blockIdx.x * 256 + threadIdx.x;
    const int c = blockIdx.y, b = blockIdx.z;
    const float k = -log1pf(__expf(-Lam[d])) * 0.125f;
    const size_t base = (((size_t)b * 4096) + (size_t)c * CLEN) * DD + d;
    float p = 1.f, h = 0.f;
#pragma unroll 4
    for (int t = 0; t < CLEN; t++) {
        const size_t ix = base + (size_t)t * DD;
        const float r = b2f(rt[ix]);
        const float i = b2f(it[ix]);
        const float xv = b2f(rg[ix]);
        const float a = __expf(k * r);
        const float g = sqrtf(fmaxf(1.f - a * a, 0.f)) * (i * xv);
        p *= a;
        h = fmaf(a, h, g);
    }
    const int o = (b * NCH + c) * DD + d;
    P[o] = p;
    Hl[o] = h;
}

__global__ __launch_bounds__(256)
void scan_carry(const float* __restrict__ P, const float* __restrict__ Hl,
                float* __restrict__ Cin)
{
    const int idx = blockIdx.x * 256 + threadIdx.x;  // B*D = 4096
    const int b = idx >> 10, d = idx & 1023;
    float h = 0.f;
    for (int c = 0; c < NCH; c++) {
        const int o = (b * NCH + c) * DD + d;
        Cin[o] = h;
        h = fmaf(P[o], h, Hl[o]);
    }
}

__global__ __launch_bounds__(256)
void scan_apply(const u16* __restrict__ rt, const u16* __restrict__ it,
                const u16* __restrict__ rg, const u16* __restrict__ lin,
                const float* __restrict__ Lam, const float* __restrict__ Cin,
                u16* __restrict__ yin)
{
    const int d = blockIdx.x * 256 + threadIdx.x;
    const int c = blockIdx.y, b = blockIdx.z;
    const float k = -log1pf(__expf(-Lam[d])) * 0.125f;
    const size_t base = (((size_t)b * 4096) + (size_t)c * CLEN) * DD + d;
    float h = Cin[(b * NCH + c) * DD + d];
#pragma unroll 4
    for (int t = 0; t < CLEN; t++) {
        const size_t ix = base + (size_t)t * DD;
        const float r = b2f(rt[ix]);
        const float i = b2f(it[ix]);
        const float xv = b2f(rg[ix]);
        const float a = __expf(k * r);
        const float g = sqrtf(fmaxf(1.f - a * a, 0.f)) * (i * xv);
        h = fmaf(a, h, g);
        const float l = b2f(lin[ix]);
        yin[ix] = f2b(gelu_f(l) * h);
    }
}

// ---------------------------------------------------------------------------
extern "C" void kernel_launch(void* const* d_in, const int* in_sizes, int n_in,
                              void* d_out, int out_size, void* d_ws, size_t ws_size,
                              hipStream_t stream)
{
    const float* x      = (const float*)d_in[0];
    const float* g1     = (const float*)d_in[1];
    const float* g2     = (const float*)d_in[2];
    const float* W_lin  = (const float*)d_in[3];
    const float* b_lin  = (const float*)d_in[4];
    const float* W_conv = (const float*)d_in[5];
    const float* b_conv = (const float*)d_in[6];
    const float* W_lin2 = (const float*)d_in[7];
    const float* b_lin2 = (const float*)d_in[8];
    const float* Wa     = (const float*)d_in[9];
    const float* ba     = (const float*)d_in[10];
    const float* Wx     = (const float*)d_in[11];
    const float* bx     = (const float*)d_in[12];
    const float* Lam    = (const float*)d_in[13];
    const float* W1     = (const float*)d_in[14];
    const float* b1     = (const float*)d_in[15];
    const float* W2     = (const float*)d_in[16];
    const float* b2     = (const float*)d_in[17];
    const float* W3     = (const float*)d_in[18];
    const float* b3     = (const float*)d_in[19];
    float* out = (float*)d_out;

    char* p = (char*)d_ws;
    auto alloc = [&](size_t bytes) -> char* {
        char* q = p;
        p += (bytes + 255) & ~(size_t)255;
        return q;
    };
    const size_t MD = (size_t)MM * DD;
    u16* wball = (u16*)alloc((size_t)8 * DD * DD * 2);
    u16* t0 = (u16*)alloc(MD * 2);
    u16* t1 = (u16*)alloc(MD * 2);
    u16* t2 = (u16*)alloc(MD * 2);
    u16* t3 = (u16*)alloc(MD * 2);
    u16* t4 = (u16*)alloc(MD * 2);
    float* res2 = (float*)alloc(MD * 4);
    float* P   = (float*)alloc((size_t)4 * NCH * DD * 4);
    float* Hl  = (float*)alloc((size_t)4 * NCH * DD * 4);
    float* Cin = (float*)alloc((size_t)4 * NCH * DD * 4);

    // weights -> bf16 (order: W_lin, W_conv, Wa, Wx, W_lin2, W1, W2, W3)
    W8 w8;
    w8.s[0] = W_lin; w8.s[1] = W_conv; w8.s[2] = Wa; w8.s[3] = Wx;
    w8.s[4] = W_lin2; w8.s[5] = W1; w8.s[6] = W2; w8.s[7] = W3;
    conv_w8<<<dim3(DD * DD / 1024, 8), 256, 0, stream>>>(w8, wball);
    u16* wbf[8];
    for (int i = 0; i < 8; i++) wbf[i] = wball + (size_t)i * DD * DD;

    const int gg = (MM / 128) * (DD / 128);   // 1024 blocks, swizzled inside
    const dim3 sg(DD / 256, NCH, 4);

    // xn = rmsnorm(x)*g1
    rmsnorm_k<<<MM, 256, 0, stream>>>(x, g1, t0);
    // lin = xn@W_lin.T + b_lin
    gemm_bt<0><<<gg, 256, 0, stream>>>(t0, wbf[0], b_lin, nullptr, t1, nullptr);
    // rg = lin@W_conv.T + b_conv
    gemm_bt<0><<<gg, 256, 0, stream>>>(t1, wbf[1], b_conv, nullptr, t2, nullptr);
    // rt = sigmoid(rg@Wa.T + ba), it = sigmoid(rg@Wx.T + bx)
    gemm_dual<0><<<gg, 256, 0, stream>>>(t2, wbf[2], wbf[3], ba, bx, t0, t3);
    // RG-LRU scan + yin = gelu(lin)*h
    scan_chunks<<<sg, 256, 0, stream>>>(t0, t3, t2, Lam, P, Hl);
    scan_carry<<<4096 / 256, 256, 0, stream>>>(P, Hl, Cin);
    scan_apply<<<sg, 256, 0, stream>>>(t0, t3, t2, t1, Lam, Cin, t4);
    // res2 = yin@W_lin2.T + b_lin2 + x
    gemm_bt<2><<<gg, 256, 0, stream>>>(t4, wbf[4], b_lin2, x, nullptr, res2);
    // xm = rmsnorm(res2)*g2
    rmsnorm_k<<<MM, 256, 0, stream>>>(res2, g2, t0);
    // combined = gelu(sigmoid(xm@W1.T+b1)) * (xm@W2.T+b2)
    gemm_dual<1><<<gg, 256, 0, stream>>>(t0, wbf[5], wbf[6], b1, b2, t2, nullptr);
    // y = combined@W3.T + b3 + res2
    gemm_bt<2><<<gg, 256, 0, stream>>>(t2, wbf[7], b3, res2, nullptr, out);
}

// Round 3
// 626.373 us; speedup vs baseline: 1.1362x; 1.0451x over previous
//
#include <hip/hip_runtime.h>
#include <cstdint>
#include <cstddef>

typedef unsigned short u16;
typedef __attribute__((ext_vector_type(8))) __bf16 bf16x8;
typedef __attribute__((ext_vector_type(4))) float f32x4;

#define DD 1024            // D
#define MM 16384           // B*T rows
#define NCH 64             // scan chunks
#define CLEN 64            // chunk length (NCH*CLEN = T = 4096)
#define EPAD 136           // epilogue LDS row stride in u16 (16B-aligned, bank-spread)

__device__ __forceinline__ u16 f2b(float f) {
    uint32_t u = __float_as_uint(f);
    u += 0x7fffu + ((u >> 16) & 1u);       // round-to-nearest-even
    return (u16)(u >> 16);
}
__device__ __forceinline__ float b2f(u16 v) {
    return __uint_as_float(((uint32_t)v) << 16);
}
__device__ __forceinline__ float sigmoid_f(float v) { return 1.f / (1.f + __expf(-v)); }
__device__ __forceinline__ float gelu_f(float v) {
    return 0.5f * v * (1.f + erff(v * 0.70710678118654752f));
}

__device__ __forceinline__ void glds16(const u16* g, u16* l) {
    __builtin_amdgcn_global_load_lds(
        (const __attribute__((address_space(1))) void*)g,
        (__attribute__((address_space(3))) void*)l, 16, 0, 0);
}

// Block swizzle: groups of 64 blocks = 8 m-tiles x 8 n-tiles; round-robin l%8
// -> XCD keeps one m-tile's A + the 2MB W set L2-resident per XCD.
__device__ __forceinline__ void swiz(int l, int& mt, int& nt) {
    const int g = l >> 6, r = l & 63;
    mt = g * 8 + (r & 7);
    nt = r >> 3;
}

// ---------------------------------------------------------------------------
// NT GEMM, software-pipelined: out[m,n] = sum_k A[m,k]*W[n,k] + bias[n].
// 128x128 tile, BK=32, 256 threads (4 waves, 2x2 of 64x64), double-buffered
// LDS with raw s_waitcnt vmcnt(4)+s_barrier (prefetch stays in flight across
// the barrier — no vmcnt(0) drain except on the last k-iter).
// MODE 0: bf16 out via LDS-staged coalesced write
// MODE 2: f32 out = v + bias + auxf[idx]
// ---------------------------------------------------------------------------
template <int MODE>
__global__ __launch_bounds__(256, 2)
void gemm_bt(const u16* __restrict__ A, const u16* __restrict__ Bw,
             const float* __restrict__ bias, const float* __restrict__ auxf,
             u16* __restrict__ outb, float* __restrict__ outf)
{
    const int K = DD, N = DD;
    __shared__ __align__(16) u16 smem[16384];   // As0 Bs0 As1 Bs1 (4096 u16 each)
    u16* const As0 = smem;
    u16* const Bs0 = smem + 4096;
    u16* const As1 = smem + 8192;
    u16* const Bs1 = smem + 12288;

    int mt, nt; swiz(blockIdx.x, mt, nt);
    const int m0 = mt * 128, n0 = nt * 128;
    const int tid = threadIdx.x;
    const int wave = tid >> 6, lane = tid & 63;
    const int wm = (wave >> 1) * 64, wn = (wave & 1) * 64;
    const int lr = lane & 15, lq = lane >> 4;

    // staging: thread stages LDS slot (trow, tcol); global kb = tcol ^ ((trow>>1)&3)
    const int trow = tid >> 2, tcol = tid & 3;
    const int kswz = (tcol ^ ((trow >> 1) & 3)) * 8;
    const u16* Ag = A + (size_t)(m0 + trow) * K + kswz;
    const u16* Bg = Bw + (size_t)(n0 + trow) * K + kswz;
    const int st = tid * 8;
    const int cs = (lq ^ ((lr >> 1) & 3)) * 8;

    f32x4 acc[4][4] = {};

    // prologue: tile 0 -> buf0
    glds16(Ag, As0 + st);
    glds16(Ag + (size_t)64 * K, As0 + st + 2048);
    glds16(Bg, Bs0 + st);
    glds16(Bg + (size_t)64 * K, Bs0 + st + 2048);

#pragma unroll 2
    for (int k0 = 0; k0 < K; k0 += 32) {
        u16* const Ac = ((k0 >> 5) & 1) ? As1 : As0;
        u16* const Bc = ((k0 >> 5) & 1) ? Bs1 : Bs0;
        if (k0 + 32 < K) {
            u16* const An = ((k0 >> 5) & 1) ? As0 : As1;
            u16* const Bn = ((k0 >> 5) & 1) ? Bs0 : Bs1;
            const int kn = k0 + 32;
            glds16(Ag + kn, An + st);
            glds16(Ag + (size_t)64 * K + kn, An + st + 2048);
            glds16(Bg + kn, Bn + st);
            glds16(Bg + (size_t)64 * K + kn, Bn + st + 2048);
            asm volatile("s_waitcnt vmcnt(4)\ns_barrier" ::: "memory");
        } else {
            asm volatile("s_waitcnt vmcnt(0)\ns_barrier" ::: "memory");
        }

        bf16x8 av[4], bv[4];
#pragma unroll
        for (int i = 0; i < 4; i++)
            av[i] = *(const bf16x8*)&Ac[(wm + i * 16 + lr) * 32 + cs];
#pragma unroll
        for (int j = 0; j < 4; j++)
            bv[j] = *(const bf16x8*)&Bc[(wn + j * 16 + lr) * 32 + cs];
#pragma unroll
        for (int i = 0; i < 4; i++)
#pragma unroll
            for (int j = 0; j < 4; j++)
                acc[i][j] = __builtin_amdgcn_mfma_f32_16x16x32_bf16(
                    av[i], bv[j], acc[i][j], 0, 0, 0);
        asm volatile("s_barrier" ::: "memory");   // protect buffer from overwrite
    }

    // epilogue: C/D layout col=lane&15, row=(lane>>4)*4+reg
    if constexpr (MODE == 0) {
        for (int half = 0; half < 2; half++) {
            __syncthreads();
            if (wm == half * 64) {
#pragma unroll
                for (int i = 0; i < 4; i++)
#pragma unroll
                    for (int j = 0; j < 4; j++) {
                        const int col = wn + j * 16 + lr;
                        const float bz = bias[n0 + col];
#pragma unroll
                        for (int p = 0; p < 4; p++)
                            smem[(i * 16 + lq * 4 + p) * EPAD + col] =
                                f2b(acc[i][j][p] + bz);
                    }
            }
            __syncthreads();
#pragma unroll
            for (int t = 0; t < 4; t++) {
                const int f = t * 256 + tid;
                const int row = f >> 4, c8 = (f & 15) * 8;
                *(uint4*)&outb[(size_t)(m0 + half * 64 + row) * N + n0 + c8] =
                    *(const uint4*)&smem[row * EPAD + c8];
            }
        }
    } else {
#pragma unroll
        for (int i = 0; i < 4; i++) {
            const int mrow = m0 + wm + i * 16 + lq * 4;
#pragma unroll
            for (int j = 0; j < 4; j++) {
                const int ncol = n0 + wn + j * 16 + lr;
                const float bz = bias[ncol];
#pragma unroll
                for (int p = 0; p < 4; p++) {
                    const size_t idx = (size_t)(mrow + p) * N + ncol;
                    outf[idx] = acc[i][j][p] + bz + auxf[idx];
                }
            }
        }
    }
}

// ---------------------------------------------------------------------------
// Dual GEMM (same A, two W), software-pipelined like gemm_bt. vmcnt(6).
// DMODE 0: out1 = sigmoid(A@B1^T+b1), out2 = sigmoid(A@B2^T+b2)  (rt, it)
// DMODE 1: out1 = gelu(sigmoid(A@B1^T+b1)) * (A@B2^T+b2)         (combined)
// ---------------------------------------------------------------------------
template <int DMODE>
__global__ __launch_bounds__(256, 2)
void gemm_dual(const u16* __restrict__ A, const u16* __restrict__ B1,
               const u16* __restrict__ B2,
               const float* __restrict__ bias1, const float* __restrict__ bias2,
               u16* __restrict__ out1, u16* __restrict__ out2)
{
    const int K = DD, N = DD;
    __shared__ __align__(16) u16 smem[24576];  // 48KB: A0 B10 B20 A1 B11 B21
    u16* const As0  = smem;
    u16* const B1s0 = smem + 4096;
    u16* const B2s0 = smem + 8192;
    u16* const As1  = smem + 12288;
    u16* const B1s1 = smem + 16384;
    u16* const B2s1 = smem + 20480;

    int mt, nt; swiz(blockIdx.x, mt, nt);
    const int m0 = mt * 128, n0 = nt * 128;
    const int tid = threadIdx.x;
    const int wave = tid >> 6, lane = tid & 63;
    const int wm = (wave >> 1) * 64, wn = (wave & 1) * 64;
    const int lr = lane & 15, lq = lane >> 4;

    const int trow = tid >> 2, tcol = tid & 3;
    const int kswz = (tcol ^ ((trow >> 1) & 3)) * 8;
    const u16* Ag  = A  + (size_t)(m0 + trow) * K + kswz;
    const u16* B1g = B1 + (size_t)(n0 + trow) * K + kswz;
    const u16* B2g = B2 + (size_t)(n0 + trow) * K + kswz;
    const int st = tid * 8;
    const int cs = (lq ^ ((lr >> 1) & 3)) * 8;

    f32x4 acc1[4][4] = {}, acc2[4][4] = {};

    // prologue: tile 0 -> buf0
    glds16(Ag, As0 + st);
    glds16(Ag + (size_t)64 * K, As0 + st + 2048);
    glds16(B1g, B1s0 + st);
    glds16(B1g + (size_t)64 * K, B1s0 + st + 2048);
    glds16(B2g, B2s0 + st);
    glds16(B2g + (size_t)64 * K, B2s0 + st + 2048);

#pragma unroll 2
    for (int k0 = 0; k0 < K; k0 += 32) {
        const int par = (k0 >> 5) & 1;
        u16* const Ac  = par ? As1  : As0;
        u16* const B1c = par ? B1s1 : B1s0;
        u16* const B2c = par ? B2s1 : B2s0;
        if (k0 + 32 < K) {
            u16* const An  = par ? As0  : As1;
            u16* const B1n = par ? B1s0 : B1s1;
            u16* const B2n = par ? B2s0 : B2s1;
            const int kn = k0 + 32;
            glds16(Ag + kn, An + st);
            glds16(Ag + (size_t)64 * K + kn, An + st + 2048);
            glds16(B1g + kn, B1n + st);
            glds16(B1g + (size_t)64 * K + kn, B1n + st + 2048);
            glds16(B2g + kn, B2n + st);
            glds16(B2g + (size_t)64 * K + kn, B2n + st + 2048);
            asm volatile("s_waitcnt vmcnt(6)\ns_barrier" ::: "memory");
        } else {
            asm volatile("s_waitcnt vmcnt(0)\ns_barrier" ::: "memory");
        }

        bf16x8 av[4], bv1[4], bv2[4];
#pragma unroll
        for (int i = 0; i < 4; i++)
            av[i] = *(const bf16x8*)&Ac[(wm + i * 16 + lr) * 32 + cs];
#pragma unroll
        for (int j = 0; j < 4; j++) {
            bv1[j] = *(const bf16x8*)&B1c[(wn + j * 16 + lr) * 32 + cs];
            bv2[j] = *(const bf16x8*)&B2c[(wn + j * 16 + lr) * 32 + cs];
        }
#pragma unroll
        for (int i = 0; i < 4; i++)
#pragma unroll
            for (int j = 0; j < 4; j++) {
                acc1[i][j] = __builtin_amdgcn_mfma_f32_16x16x32_bf16(
                    av[i], bv1[j], acc1[i][j], 0, 0, 0);
                acc2[i][j] = __builtin_amdgcn_mfma_f32_16x16x32_bf16(
                    av[i], bv2[j], acc2[i][j], 0, 0, 0);
            }
        asm volatile("s_barrier" ::: "memory");
    }

    if constexpr (DMODE == 0) {
#pragma unroll
        for (int o = 0; o < 2; o++) {
            const float* bz = o ? bias2 : bias1;
            u16* op = o ? out2 : out1;
            for (int half = 0; half < 2; half++) {
                __syncthreads();
                if (wm == half * 64) {
#pragma unroll
                    for (int i = 0; i < 4; i++)
#pragma unroll
                        for (int j = 0; j < 4; j++) {
                            const int col = wn + j * 16 + lr;
                            const float bb = bz[n0 + col];
#pragma unroll
                            for (int p = 0; p < 4; p++) {
                                const float v = (o ? acc2[i][j][p] : acc1[i][j][p]) + bb;
                                smem[(i * 16 + lq * 4 + p) * EPAD + col] = f2b(sigmoid_f(v));
                            }
                        }
                }
                __syncthreads();
#pragma unroll
                for (int t = 0; t < 4; t++) {
                    const int f = t * 256 + tid;
                    const int row = f >> 4, c8 = (f & 15) * 8;
                    *(uint4*)&op[(size_t)(m0 + half * 64 + row) * N + n0 + c8] =
                        *(const uint4*)&smem[row * EPAD + c8];
                }
            }
        }
    } else {
        for (int half = 0; half < 2; half++) {
            __syncthreads();
            if (wm == half * 64) {
#pragma unroll
                for (int i = 0; i < 4; i++)
#pragma unroll
                    for (int j = 0; j < 4; j++) {
                        const int col = wn + j * 16 + lr;
                        const float bb1 = bias1[n0 + col];
                        const float bb2 = bias2[n0 + col];
#pragma unroll
                        for (int p = 0; p < 4; p++) {
                            const float g = gelu_f(sigmoid_f(acc1[i][j][p] + bb1));
                            smem[(i * 16 + lq * 4 + p) * EPAD + col] =
                                f2b(g * (acc2[i][j][p] + bb2));
                        }
                    }
            }
            __syncthreads();
#pragma unroll
            for (int t = 0; t < 4; t++) {
                const int f = t * 256 + tid;
                const int row = f >> 4, c8 = (f & 15) * 8;
                *(uint4*)&out1[(size_t)(m0 + half * 64 + row) * N + n0 + c8] =
                    *(const uint4*)&smem[row * EPAD + c8];
            }
        }
    }
}

// ---------------------------------------------------------------------------
// RMSNorm: one block per row; out bf16 = x/max(||x||,1e-12)*sqrt(D)*g
// ---------------------------------------------------------------------------
__global__ __launch_bounds__(256)
void rmsnorm_k(const float* __restrict__ x, const float* __restrict__ g,
               u16* __restrict__ out)
{
    const int row = blockIdx.x;
    const int t = threadIdx.x;
    const float4 v = ((const float4*)(x + (size_t)row * DD))[t];
    float ss = v.x * v.x + v.y * v.y + v.z * v.z + v.w * v.w;
#pragma unroll
    for (int o = 32; o > 0; o >>= 1) ss += __shfl_down(ss, o, 64);
    __shared__ float wsum[4];
    if ((t & 63) == 0) wsum[t >> 6] = ss;
    __syncthreads();
    const float tot = wsum[0] + wsum[1] + wsum[2] + wsum[3];
    const float sc = 32.0f * rsqrtf(fmaxf(tot, 1e-24f));
    const float4 gv = ((const float4*)g)[t];
    ushort4 o4;
    o4.x = f2b(v.x * sc * gv.x);
    o4.y = f2b(v.y * sc * gv.y);
    o4.z = f2b(v.z * sc * gv.z);
    o4.w = f2b(v.w * sc * gv.w);
    ((ushort4*)(out + (size_t)row * DD))[t] = o4;
}

// ---------------------------------------------------------------------------
// fp32 -> bf16 conversion of all 8 weight matrices in one launch
// ---------------------------------------------------------------------------
struct W8 { const float* s[8]; };
__global__ __launch_bounds__(256)
void conv_w8(W8 w, u16* __restrict__ out)
{
    const float* in = w.s[blockIdx.y];
    u16* o = out + (size_t)blockIdx.y * DD * DD;
    const int i = (blockIdx.x * 256 + threadIdx.x) * 4;
    const float4 v = *(const float4*)(in + i);
    ushort4 r;
    r.x = f2b(v.x); r.y = f2b(v.y); r.z = f2b(v.z); r.w = f2b(v.w);
    *(ushort4*)(o + i) = r;
}

// ---------------------------------------------------------------------------
// RG-LRU chunked scan. h[t] = a[t]*h[t-1] + g[t]
// a = exp(log_a * rt / 8), log_a = -softplus(-Lam[d])
// g = sqrt(1-a^2) * it * x_rg
// ---------------------------------------------------------------------------
__global__ __launch_bounds__(256)
void scan_chunks(const u16* __restrict__ rt, const u16* __restrict__ it,
                 const u16* __restrict__ rg, const float* __restrict__ Lam,
                 float* __restrict__ P, float* __restrict__ Hl)
{
    const int d = blockIdx.x * 256 + threadIdx.x;
    const int c = blockIdx.y, b = blockIdx.z;
    const float k = -log1pf(__expf(-Lam[d])) * 0.125f;
    const size_t base = (((size_t)b * 4096) + (size_t)c * CLEN) * DD + d;
    float p = 1.f, h = 0.f;
#pragma unroll 4
    for (int t = 0; t < CLEN; t++) {
        const size_t ix = base + (size_t)t * DD;
        const float r = b2f(rt[ix]);
        const float i = b2f(it[ix]);
        const float xv = b2f(rg[ix]);
        const float a = __expf(k * r);
        const float g = sqrtf(fmaxf(1.f - a * a, 0.f)) * (i * xv);
        p *= a;
        h = fmaf(a, h, g);
    }
    const int o = (b * NCH + c) * DD + d;
    P[o] = p;
    Hl[o] = h;
}

__global__ __launch_bounds__(256)
void scan_carry(const float* __restrict__ P, const float* __restrict__ Hl,
                float* __restrict__ Cin)
{
    const int idx = blockIdx.x * 256 + threadIdx.x;  // B*D = 4096
    const int b = idx >> 10, d = idx & 1023;
    float h = 0.f;
    for (int c = 0; c < NCH; c++) {
        const int o = (b * NCH + c) * DD + d;
        Cin[o] = h;
        h = fmaf(P[o], h, Hl[o]);
    }
}

__global__ __launch_bounds__(256)
void scan_apply(const u16* __restrict__ rt, const u16* __restrict__ it,
                const u16* __restrict__ rg, const u16* __restrict__ lin,
                const float* __restrict__ Lam, const float* __restrict__ Cin,
                u16* __restrict__ yin)
{
    const int d = blockIdx.x * 256 + threadIdx.x;
    const int c = blockIdx.y, b = blockIdx.z;
    const float k = -log1pf(__expf(-Lam[d])) * 0.125f;
    const size_t base = (((size_t)b * 4096) + (size_t)c * CLEN) * DD + d;
    float h = Cin[(b * NCH + c) * DD + d];
#pragma unroll 4
    for (int t = 0; t < CLEN; t++) {
        const size_t ix = base + (size_t)t * DD;
        const float r = b2f(rt[ix]);
        const float i = b2f(it[ix]);
        const float xv = b2f(rg[ix]);
        const float a = __expf(k * r);
        const float g = sqrtf(fmaxf(1.f - a * a, 0.f)) * (i * xv);
        h = fmaf(a, h, g);
        const float l = b2f(lin[ix]);
        yin[ix] = f2b(gelu_f(l) * h);
    }
}

// ---------------------------------------------------------------------------
extern "C" void kernel_launch(void* const* d_in, const int* in_sizes, int n_in,
                              void* d_out, int out_size, void* d_ws, size_t ws_size,
                              hipStream_t stream)
{
    const float* x      = (const float*)d_in[0];
    const float* g1     = (const float*)d_in[1];
    const float* g2     = (const float*)d_in[2];
    const float* W_lin  = (const float*)d_in[3];
    const float* b_lin  = (const float*)d_in[4];
    const float* W_conv = (const float*)d_in[5];
    const float* b_conv = (const float*)d_in[6];
    const float* W_lin2 = (const float*)d_in[7];
    const float* b_lin2 = (const float*)d_in[8];
    const float* Wa     = (const float*)d_in[9];
    const float* ba     = (const float*)d_in[10];
    const float* Wx     = (const float*)d_in[11];
    const float* bx     = (const float*)d_in[12];
    const float* Lam    = (const float*)d_in[13];
    const float* W1     = (const float*)d_in[14];
    const float* b1     = (const float*)d_in[15];
    const float* W2     = (const float*)d_in[16];
    const float* b2     = (const float*)d_in[17];
    const float* W3     = (const float*)d_in[18];
    const float* b3     = (const float*)d_in[19];
    float* out = (float*)d_out;

    char* p = (char*)d_ws;
    auto alloc = [&](size_t bytes) -> char* {
        char* q = p;
        p += (bytes + 255) & ~(size_t)255;
        return q;
    };
    const size_t MD = (size_t)MM * DD;
    u16* wball = (u16*)alloc((size_t)8 * DD * DD * 2);
    u16* t0 = (u16*)alloc(MD * 2);
    u16* t1 = (u16*)alloc(MD * 2);
    u16* t2 = (u16*)alloc(MD * 2);
    u16* t3 = (u16*)alloc(MD * 2);
    u16* t4 = (u16*)alloc(MD * 2);
    float* res2 = (float*)alloc(MD * 4);
    float* P   = (float*)alloc((size_t)4 * NCH * DD * 4);
    float* Hl  = (float*)alloc((size_t)4 * NCH * DD * 4);
    float* Cin = (float*)alloc((size_t)4 * NCH * DD * 4);

    // weights -> bf16 (order: W_lin, W_conv, Wa, Wx, W_lin2, W1, W2, W3)
    W8 w8;
    w8.s[0] = W_lin; w8.s[1] = W_conv; w8.s[2] = Wa; w8.s[3] = Wx;
    w8.s[4] = W_lin2; w8.s[5] = W1; w8.s[6] = W2; w8.s[7] = W3;
    conv_w8<<<dim3(DD * DD / 1024, 8), 256, 0, stream>>>(w8, wball);
    u16* wbf[8];
    for (int i = 0; i < 8; i++) wbf[i] = wball + (size_t)i * DD * DD;

    const int gg = (MM / 128) * (DD / 128);   // 1024 blocks, swizzled inside
    const dim3 sg(DD / 256, NCH, 4);

    // xn = rmsnorm(x)*g1
    rmsnorm_k<<<MM, 256, 0, stream>>>(x, g1, t0);
    // lin = xn@W_lin.T + b_lin
    gemm_bt<0><<<gg, 256, 0, stream>>>(t0, wbf[0], b_lin, nullptr, t1, nullptr);
    // rg = lin@W_conv.T + b_conv
    gemm_bt<0><<<gg, 256, 0, stream>>>(t1, wbf[1], b_conv, nullptr, t2, nullptr);
    // rt = sigmoid(rg@Wa.T + ba), it = sigmoid(rg@Wx.T + bx)
    gemm_dual<0><<<gg, 256, 0, stream>>>(t2, wbf[2], wbf[3], ba, bx, t0, t3);
    // RG-LRU scan + yin = gelu(lin)*h
    scan_chunks<<<sg, 256, 0, stream>>>(t0, t3, t2, Lam, P, Hl);
    scan_carry<<<4096 / 256, 256, 0, stream>>>(P, Hl, Cin);
    scan_apply<<<sg, 256, 0, stream>>>(t0, t3, t2, t1, Lam, Cin, t4);
    // res2 = yin@W_lin2.T + b_lin2 + x
    gemm_bt<2><<<gg, 256, 0, stream>>>(t4, wbf[4], b_lin2, x, nullptr, res2);
    // xm = rmsnorm(res2)*g2
    rmsnorm_k<<<MM, 256, 0, stream>>>(res2, g2, t0);
    // combined = gelu(sigmoid(xm@W1.T+b1)) * (xm@W2.T+b2)
    gemm_dual<1><<<gg, 256, 0, stream>>>(t0, wbf[5], wbf[6], b1, b2, t2, nullptr);
    // y = combined@W3.T + b3 + res2
    gemm_bt<2><<<gg, 256, 0, stream>>>(t2, wbf[7], b3, res2, nullptr, out);
}